// Round 6
// baseline (801.213 us; speedup 1.0000x reference)
//
#include <hip/hip_runtime.h>
#include <math.h>

#define NPTS 400000
#define K27  27
#define NBLK 3136          // 8 XCD chunks x 392; 3136*128 = 401408 >= NPTS

typedef unsigned short u16;
typedef __bf16 bf16x8 __attribute__((ext_vector_type(8)));
typedef float  f32x4  __attribute__((ext_vector_type(4)));

__device__ __forceinline__ u16 f2bf(float f) {
    unsigned u = __float_as_uint(f);
    u += 0x7FFFu + ((u >> 16) & 1u);   // RNE round to bf16
    return (u16)(u >> 16);
}
__device__ __forceinline__ unsigned pack2(float lo, float hi) {
    return (unsigned)f2bf(lo) | ((unsigned)f2bf(hi) << 16);
}

// ---------------------------------------------------------------------------
// prep: transpose+pad W1 [27][64][38] -> W1t [27][48][64] bf16 (n-major, k-contig)
//       and W2 [27][38][38] -> W2t [27][48][64] bf16; also zero h pad row N.
// ---------------------------------------------------------------------------
__global__ void prep_w(const float* __restrict__ W1, const float* __restrict__ W2,
                       u16* __restrict__ W1t, u16* __restrict__ W2t,
                       u16* __restrict__ h)
{
    int i = blockIdx.x * 256 + threadIdx.x;
    if (blockIdx.x == 0 && threadIdx.x < 64)
        h[(size_t)NPTS * 64 + threadIdx.x] = 0;   // zero pad-row of h
    const int TOT = K27 * 48 * 64;
    if (i >= TOT) return;
    int k  = i / (48 * 64);
    int r  = i % (48 * 64);
    int n  = r >> 6;    // 0..47 (out channel)
    int kc = r & 63;    // 0..63 (in channel)
    u16 w1 = 0, w2 = 0;
    if (n < 38) {
        w1 = f2bf(W1[(k * 64 + kc) * 38 + n]);
        if (kc < 38) w2 = f2bf(W2[(k * 38 + kc) * 38 + n]);
    }
    W1t[i] = w1;
    W2t[i] = w2;
}

// ---------------------------------------------------------------------------
// prep: features fp32 [N][64] -> bf16 [N+1][64] (row N zeroed), 8 elems/thread
// ---------------------------------------------------------------------------
__global__ void prep_feat(const float* __restrict__ F, u16* __restrict__ Fb)
{
    size_t i = (size_t)blockIdx.x * 256 + threadIdx.x;     // chunk of 8 elems
    const size_t TOTV = (size_t)NPTS * 8;                  // valid chunks
    const size_t TOT  = (size_t)(NPTS + 1) * 8;
    if (i >= TOT) return;
    uint4 v = {0, 0, 0, 0};
    if (i < TOTV) {
        const float4* fp = (const float4*)(F + i * 8);
        float4 a = fp[0], b = fp[1];
        v.x = pack2(a.x, a.y); v.y = pack2(a.z, a.w);
        v.z = pack2(b.x, b.y); v.w = pack2(b.z, b.w);
    }
    *(uint4*)(Fb + i * 8) = v;
}

// ---------------------------------------------------------------------------
// A-fragment gather for one m-tile (2 x 16B per lane).
// BF16IN: rows are bf16[64], pad row exists at idx==NPTS (zeros).
// !BF16IN: rows are fp32[64]; pad handled by clamp + zero.
// ---------------------------------------------------------------------------
template<bool BF16IN>
__device__ __forceinline__ void gather2(const void* __restrict__ in_, int id, int quad,
                                        bf16x8* a0, bf16x8* a1)
{
    if (BF16IN) {
        const u16* rowp = (const u16*)in_ + (size_t)id * 64 + quad * 8;
        *a0 = *(const bf16x8*)(rowp);
        *a1 = *(const bf16x8*)(rowp + 32);
    } else {
        bool pad = (id >= NPTS);
        int ic = pad ? 0 : id;
        const float* rowp = (const float*)in_ + (size_t)ic * 64 + quad * 8;
        float4 f0 = *(const float4*)(rowp);
        float4 f1 = *(const float4*)(rowp + 4);
        float4 f2 = *(const float4*)(rowp + 32);
        float4 f3 = *(const float4*)(rowp + 36);
        uint4 v0, v1;
        v0.x = pack2(f0.x, f0.y); v0.y = pack2(f0.z, f0.w);
        v0.z = pack2(f1.x, f1.y); v0.w = pack2(f1.z, f1.w);
        v1.x = pack2(f2.x, f2.y); v1.y = pack2(f2.z, f2.w);
        v1.z = pack2(f3.x, f3.y); v1.w = pack2(f3.z, f3.w);
        if (pad) { v0 = uint4{0,0,0,0}; v1 = uint4{0,0,0,0}; }
        *a0 = *(const bf16x8*)&v0;
        *a1 = *(const bf16x8*)&v1;
    }
}

// ---------------------------------------------------------------------------
// One MFMA stage: load B fragments for offset k (L1-hot) and do 2x3x2 MFMAs.
// ---------------------------------------------------------------------------
__device__ __forceinline__ void mfma_stage(const u16* __restrict__ wk, int l16, int quad,
                                           const bf16x8 (&A)[2][2], f32x4 (&acc)[2][3])
{
    bf16x8 B0[3], B1[3];
    #pragma unroll
    for (int nt = 0; nt < 3; ++nt) {
        const u16* brow = wk + (nt * 16 + l16) * 64 + quad * 8;
        B0[nt] = *(const bf16x8*)(brow);
        B1[nt] = *(const bf16x8*)(brow + 32);
    }
    #pragma unroll
    for (int mt = 0; mt < 2; ++mt)
        #pragma unroll
        for (int nt = 0; nt < 3; ++nt) {
            acc[mt][nt] = __builtin_amdgcn_mfma_f32_16x16x32_bf16(A[mt][0], B0[nt], acc[mt][nt], 0, 0, 0);
            acc[mt][nt] = __builtin_amdgcn_mfma_f32_16x16x32_bf16(A[mt][1], B1[nt], acc[mt][nt], 0, 0, 0);
        }
}

// ---------------------------------------------------------------------------
// Barrier-free, LDS-free, software-pipelined gather-GEMM layer.
// 1 wave = 32 points (2 m-tiles) x 48 (padded) out channels.
// Block = 4 waves = 128 points.  (R3-R5 bug: used logical*256 with 32-pt
// waves -> half the points never computed -> poisoned h / zero out.)
// Explicit double buffer A0/A1; idx + A prefetched one MFMA-stage ahead.
// LAYER==1: input rows -> GELU -> h bf16 [N+1][64] (cols>=38 zero)
// LAYER==2: bf16 h in -> fp32 out [N][38]
// ---------------------------------------------------------------------------
template<int LAYER, bool BF16IN>
__global__ __launch_bounds__(256)
void spconv(const void* __restrict__ in_, const int* __restrict__ nbr,
            const u16* __restrict__ Wt, void* __restrict__ out_)
{
    const int t    = threadIdx.x;
    const int wave = t >> 6;
    const int lane = t & 63;
    const int quad = lane >> 4;
    const int l16  = lane & 15;

    // XCD-chunk swizzle: contiguous point range per XCD for L2 locality.
    const int b       = blockIdx.x;
    const int logical = (b & 7) * (NBLK / 8) + (b >> 3);
    const int wbase   = logical * 128 + wave * 32;   // this wave's first point
    if (wbase >= NPTS) return;                        // no barriers -> safe

    f32x4 acc[2][3] = {};   // [m-tile][n-tile]

    int nrow[2];
    #pragma unroll
    for (int mt = 0; mt < 2; ++mt) {
        int r = wbase + mt * 16 + l16;
        nrow[mt] = (r < NPTS) ? r : (NPTS - 1);      // clamp; result discarded
    }

    bf16x8 A0[2][2], A1[2][2];
    int iA[2], iB[2];

    // ---- prologue: k=0 fragments + k=1 indices ----
    #pragma unroll
    for (int mt = 0; mt < 2; ++mt) iA[mt] = nbr[nrow[mt]];
    #pragma unroll
    for (int mt = 0; mt < 2; ++mt) gather2<BF16IN>(in_, iA[mt], quad, &A0[mt][0], &A0[mt][1]);
    #pragma unroll
    for (int mt = 0; mt < 2; ++mt) iB[mt] = nbr[(size_t)NPTS + nrow[mt]];

    // 27 = 13 pairs (k=0..25) + tail (k=26)
    for (int kp = 0; kp < 13; ++kp) {
        const int k0 = 2 * kp;
        // gather A1 <- offset k0+1 (indices in iB)
        #pragma unroll
        for (int mt = 0; mt < 2; ++mt) gather2<BF16IN>(in_, iB[mt], quad, &A1[mt][0], &A1[mt][1]);
        // prefetch idx for k0+2 (always valid: k0+2 <= 26)
        #pragma unroll
        for (int mt = 0; mt < 2; ++mt) iA[mt] = nbr[(size_t)(k0 + 2) * NPTS + nrow[mt]];
        // MFMA offset k0 (A0 gathered one stage earlier)
        mfma_stage(Wt + (size_t)k0 * 48 * 64, l16, quad, A0, acc);
        // gather A0 <- offset k0+2
        #pragma unroll
        for (int mt = 0; mt < 2; ++mt) gather2<BF16IN>(in_, iA[mt], quad, &A0[mt][0], &A0[mt][1]);
        // prefetch idx for k0+3 (guard: kp==12 -> k0+3==27, skip)
        if (kp < 12) {
            #pragma unroll
            for (int mt = 0; mt < 2; ++mt) iB[mt] = nbr[(size_t)(k0 + 3) * NPTS + nrow[mt]];
        }
        // MFMA offset k0+1
        mfma_stage(Wt + (size_t)(k0 + 1) * 48 * 64, l16, quad, A1, acc);
    }
    // tail: k=26 (A0 gathered in last pair)
    mfma_stage(Wt + (size_t)26 * 48 * 64, l16, quad, A0, acc);

    // ---- epilogue ----
    if (LAYER == 1) {
        u16* h = (u16*)out_;
        #pragma unroll
        for (int mt = 0; mt < 2; ++mt) {
            int row0 = wbase + mt * 16 + quad * 4;
            #pragma unroll
            for (int r = 0; r < 4; ++r) {
                int row = row0 + r;
                if (row < NPTS) {
                    #pragma unroll
                    for (int nt = 0; nt < 3; ++nt) {
                        float x = acc[mt][nt][r];
                        float g = 0.5f * x * (1.0f + erff(x * 0.70710678118654752f));
                        h[(size_t)row * 64 + nt * 16 + l16] = f2bf(g);
                    }
                    h[(size_t)row * 64 + 48 + l16] = 0;   // zero pad cols 48..63
                }
            }
        }
    } else {
        float* out = (float*)out_;
        #pragma unroll
        for (int mt = 0; mt < 2; ++mt) {
            int row0 = wbase + mt * 16 + quad * 4;
            #pragma unroll
            for (int nt = 0; nt < 3; ++nt) {
                int col = nt * 16 + l16;
                if (col < 38) {
                    #pragma unroll
                    for (int r = 0; r < 4; ++r) {
                        int row = row0 + r;
                        if (row < NPTS)
                            out[(size_t)row * 38 + col] = acc[mt][nt][r];
                    }
                }
            }
        }
    }
}

// ---------------------------------------------------------------------------
extern "C" void kernel_launch(void* const* d_in, const int* in_sizes, int n_in,
                              void* d_out, int out_size, void* d_ws, size_t ws_size,
                              hipStream_t stream)
{
    const float* feat = (const float*)d_in[0];   // [N][64] fp32
    const int*   nbr  = (const int*)  d_in[1];   // [27][N] int32, N == pad idx
    const float* W1   = (const float*)d_in[2];   // [27][64][38]
    const float* W2   = (const float*)d_in[3];   // [27][38][38]

    const size_t hbytes = (size_t)(NPTS + 1) * 64 * 2;   // 51.2 MB, bf16 rows
    const size_t wbytes = (size_t)K27 * 48 * 64 * 2;     // 165,888

    char* ws = (char*)d_ws;
    u16* h   = (u16*)ws;
    u16* W1t = (u16*)(ws + hbytes);
    u16* W2t = (u16*)(ws + hbytes + wbytes);
    u16* Fb  = (u16*)(ws + hbytes + 2 * wbytes);
    const bool full = ws_size >= 2 * hbytes + 2 * wbytes;  // bf16 feature copy fits?

    prep_w<<<(K27 * 48 * 64 + 255) / 256, 256, 0, stream>>>(W1, W2, W1t, W2t, h);

    if (full) {
        prep_feat<<<(int)(((size_t)(NPTS + 1) * 8 + 255) / 256), 256, 0, stream>>>(feat, Fb);
        spconv<1, true ><<<NBLK, 256, 0, stream>>>(Fb,   nbr, W1t, h);
    } else {
        spconv<1, false><<<NBLK, 256, 0, stream>>>(feat, nbr, W1t, h);
    }
    spconv<2, true ><<<NBLK, 256, 0, stream>>>(h, nbr, W2t, d_out);
}